// Round 5
// baseline (5243.872 us; speedup 1.0000x reference)
//
#include <hip/hip_runtime.h>

#define AG __HIP_MEMORY_SCOPE_AGENT
#define B_ 16
#define T_ 512
#define P_ 2048
#define SN_ 256
#define SD_ 1024
#define NGD 8                 // den groups (one b-pair each)
#define GB 16                 // blocks per den group (64 cols each)
#define NBD (NGD * GB)        // 128 den blocks
#define NBLK (NBD + B_)       // + 16 num blocks = 144
#define NTHR 1024
#define CHS 160               // chunk stride in floats (128 data + 2 M + pad)

__device__ __forceinline__ float alf(const float* p){ return __hip_atomic_load(p, __ATOMIC_RELAXED, AG); }
__device__ __forceinline__ void  asf(float* p, float v){ __hip_atomic_store(p, v, __ATOMIC_RELAXED, AG); }
__device__ __forceinline__ void  rsu(unsigned* p, unsigned v){ __hip_atomic_store(p, v, __ATOMIC_RELEASE, AG); }
__device__ __forceinline__ void wait_eq(unsigned* p, unsigned v){
  while (__hip_atomic_load(p, __ATOMIC_RELAXED, AG) != v) __builtin_amdgcn_s_sleep(1);
  asm volatile("" ::: "memory");   // keep data loads after the flag match
}

// Exp-space forward recursion, producer/consumer dataflow (no grid barrier):
//   q_t[b,c] = (sum_k q_{t-1}[b,k] * W[k,c]) / M[b] * exp(e_t[b,c])
// den: 8 groups x 16 blocks; group owns b-pair {2g,2g+1}; block owns 64 cols.
// W lives in REGISTERS (64 fp32/thread, loaded once) — zero per-step W LDS.
// Exchange: 512B chunk + epoch flag (exact-match), 2 parities; publish and
// release all from wave 0 (release store orders wave-0 stores -> no sync).
// num: fully block-local, W in registers, 16 independent blocks.
__global__ __launch_bounds__(NTHR) void lfmmi_kernel(
    const float* __restrict__ input, const int* __restrict__ seqlen,
    const float* __restrict__ num_init, const float* __restrict__ num_trans,
    const float* __restrict__ num_final, const int* __restrict__ num_pdf,
    const float* __restrict__ den_init, const float* __restrict__ den_trans,
    const float* __restrict__ den_final, const int* __restrict__ den_pdf,
    float* __restrict__ out, float* __restrict__ ws)
{
  __shared__ __align__(16) unsigned char smem[24832];
  const int tid = threadIdx.x;
  const int bid = blockIdx.x;

  // workspace carve
  float*    Qc     = ws;                               // [2][NGD][GB][CHS]
  unsigned* F      = (unsigned*)(Qc + 2*NGD*GB*CHS);   // [2][NGD][GB][16]
  float*    DenRes = (float*)(F + 2*NGD*GB*16);        // [16]
  float*    NumRes = DenRes + 16;                      // [16]
  unsigned* DF     = (unsigned*)(NumRes + 16);         // [NGD][16]
  unsigned* NF     = DF + NGD*16;                      // [16][16]

  const int wv = tid >> 6, ln = tid & 63;

  if (bid < NBD) {
    // ================= DEN =================
    const int g = bid >> 4, r = bid & 15;
    const int cg = tid & 31, kq = tid >> 5;   // tile: cols {cg, cg+32}, k-slice 32
    const int col0 = r * 64;

    float* qs    = (float*)smem;              // [2][2][1024] 16 KB (parity,b,col)
    float2* red2 = (float2*)(smem + 16384);   // [16][64] 8 KB
    float* Ms    = (float*)(smem + 24576);    // [2][2] (parity, b)

    // --- W into registers: wA/wB[kk] = exp(trans[kq*32+kk][col0+cg(+32)]) ---
    float wA[32], wB[32];
    {
      const float* wb = den_trans + (size_t)(kq * 32) * SD_ + col0 + cg;
      #pragma unroll
      for (int kk = 0; kk < 32; ++kk) {
        wA[kk] = __expf(wb[(size_t)kk * SD_]);
        wB[kk] = __expf(wb[(size_t)kk * SD_ + 32]);
      }
    }

    const int b0 = 2 * g, b1 = 2 * g + 1;
    const int slen0 = seqlen[b0], slen1 = seqlen[b1];
    const size_t inb0 = (size_t)b0 * T_ * P_, inb1 = (size_t)b1 * T_ * P_;
    int pdf0 = 0;
    if (wv == 0) pdf0 = den_pdf[col0 + ln];

    // --- init publish (t=0, parity 0) — wave 0 only ---
    if (wv == 0) {
      float* ch0 = Qc + ((size_t)(0 * NGD + g) * GB + r) * CHS;
      const float v0 = __expf(den_init[col0 + ln] + input[inb0 + pdf0]);
      const float v1 = __expf(den_init[col0 + ln] + input[inb1 + pdf0]);
      asf(ch0 + ln, v0); asf(ch0 + 64 + ln, v1);
      if (r == 0) {
        float m0 = v0, m1 = v1;
        #pragma unroll
        for (int d = 1; d < 64; d <<= 1) {
          m0 = fmaxf(m0, __shfl_xor(m0, d));
          m1 = fmaxf(m1, __shfl_xor(m1, d));
        }
        if (ln == 0) { asf(ch0 + 128, m0); asf(ch0 + 129, m1); }
      }
      if (tid == 0) rsu(F + ((0 * NGD + g) * GB + r) * 16, 0u);  // orders wave-0 stores
    }

    float Lr0 = 0.f, Lr1 = 0.f;
    for (int t = 1; t <= 511; ++t) {
      const int pp = (t - 1) & 1, pc = t & 1;
      float e0 = 0.f, e1 = 0.f;
      if (wv == 0) {   // emission gather prefetch (unconditional; hidden by compute)
        e0 = input[inb0 + (size_t)t * P_ + pdf0];
        e1 = input[inb1 + (size_t)t * P_ + pdf0];
      }
      // stage q_{t-1}: wave wv polls producer wv's flag, loads its chunk
      wait_eq(F + ((pp * NGD + g) * GB + wv) * 16, (unsigned)(t - 1));
      {
        const float* ch = Qc + ((size_t)(pp * NGD + g) * GB + wv) * CHS;
        qs[pp * 2048 + wv * 64 + ln]        = alf(ch + ln);
        qs[pp * 2048 + 1024 + wv * 64 + ln] = alf(ch + 64 + ln);
        if (wv == 0 && ln < 2) Ms[pp * 2 + ln] = alf(ch + 128 + ln);
      }
      __syncthreads();
      // compute 2c x 2b tile over k-slice 32; q via half-wave LDS broadcast
      const float* q0 = qs + pp * 2048 + kq * 32;
      const float* q1 = q0 + 1024;
      float a00 = 0.f, a01 = 0.f, a10 = 0.f, a11 = 0.f;
      #pragma unroll
      for (int jj = 0; jj < 8; ++jj) {
        const float4 f0 = *(const float4*)(q0 + 4 * jj);
        const float4 f1 = *(const float4*)(q1 + 4 * jj);
        a00 = fmaf(f0.x, wA[4*jj+0], a00); a00 = fmaf(f0.y, wA[4*jj+1], a00);
        a00 = fmaf(f0.z, wA[4*jj+2], a00); a00 = fmaf(f0.w, wA[4*jj+3], a00);
        a01 = fmaf(f0.x, wB[4*jj+0], a01); a01 = fmaf(f0.y, wB[4*jj+1], a01);
        a01 = fmaf(f0.z, wB[4*jj+2], a01); a01 = fmaf(f0.w, wB[4*jj+3], a01);
        a10 = fmaf(f1.x, wA[4*jj+0], a10); a10 = fmaf(f1.y, wA[4*jj+1], a10);
        a10 = fmaf(f1.z, wA[4*jj+2], a10); a10 = fmaf(f1.w, wA[4*jj+3], a10);
        a11 = fmaf(f1.x, wB[4*jj+0], a11); a11 = fmaf(f1.y, wB[4*jj+1], a11);
        a11 = fmaf(f1.z, wB[4*jj+2], a11); a11 = fmaf(f1.w, wB[4*jj+3], a11);
      }
      a00 += __shfl_xor(a00, 32); a01 += __shfl_xor(a01, 32);
      a10 += __shfl_xor(a10, 32); a11 += __shfl_xor(a11, 32);
      if (ln < 32) {
        red2[wv * 64 + cg]      = make_float2(a00, a10);
        red2[wv * 64 + 32 + cg] = make_float2(a01, a11);
      }
      __syncthreads();
      // wave 0: fold 16 partials, scale, publish, release (no extra sync)
      if (wv == 0) {
        float acc0 = 0.f, acc1 = 0.f;
        #pragma unroll
        for (int w = 0; w < 16; ++w) {
          const float2 v = red2[w * 64 + ln];
          acc0 += v.x; acc1 += v.y;
        }
        const float Mv0 = Ms[pp * 2 + 0], Mv1 = Ms[pp * 2 + 1];
        const float v0 = (t < slen0) ? (acc0 / Mv0) * __expf(e0)
                                     : qs[pp * 2048 + col0 + ln];
        const float v1 = (t < slen1) ? (acc1 / Mv1) * __expf(e1)
                                     : qs[pp * 2048 + 1024 + col0 + ln];
        float* ch = Qc + ((size_t)(pc * NGD + g) * GB + r) * CHS;
        asf(ch + ln, v0); asf(ch + 64 + ln, v1);
        if (r == 0) {
          float m0 = v0, m1 = v1;
          #pragma unroll
          for (int d = 1; d < 64; d <<= 1) {
            m0 = fmaxf(m0, __shfl_xor(m0, d));
            m1 = fmaxf(m1, __shfl_xor(m1, d));
          }
          if (ln == 0) {
            asf(ch + 128, m0); asf(ch + 129, m1);
            if (t < slen0) Lr0 += __logf(Mv0);
            if (t < slen1) Lr1 += __logf(Mv1);
          }
        }
        if (tid == 0) rsu(F + ((pc * NGD + g) * GB + r) * 16, (unsigned)t);
      }
    }

    // --- epilogue: r==0 blocks reduce final q (t=511, parity 1) ---
    if (r == 0) {
      wait_eq(F + ((1 * NGD + g) * GB + wv) * 16, 511u);
      {
        const float* ch = Qc + ((size_t)(1 * NGD + g) * GB + wv) * CHS;
        qs[2048 + wv * 64 + ln]        = alf(ch + ln);        // parity-1 region:
        qs[2048 + 1024 + wv * 64 + ln] = alf(ch + 64 + ln);   // avoids fold's carry reads
      }
      __syncthreads();
      float* red = (float*)red2;   // 2048 floats
      const int b2e = tid >> 9, ce = tid & 511;
      red[tid] = qs[2048 + b2e * 1024 + ce] * __expf(den_final[ce])
               + qs[2048 + b2e * 1024 + 512 + ce] * __expf(den_final[512 + ce]);
      __syncthreads();
      for (int off = 256; off; off >>= 1) {
        const int base = (tid >= 512) ? 512 : 0, i = tid - base;
        if (i < off) red[base + i] += red[base + i + off];
        __syncthreads();
      }
      if (tid == 0) {
        asf(DenRes + 2 * g,     Lr0 + __logf(red[0]));
        asf(DenRes + 2 * g + 1, Lr1 + __logf(red[512]));
        rsu(DF + g * 16, 0x600D0000u | (unsigned)g);
        if (g == 0) {
          for (int g2 = 0; g2 < NGD; ++g2) wait_eq(DF + g2 * 16, 0x600D0000u | (unsigned)g2);
          for (int b2 = 0; b2 < B_; ++b2)  wait_eq(NF + b2 * 16, 0x600D0100u | (unsigned)b2);
          float sden = 0.f, snum = 0.f;
          for (int i = 0; i < 16; ++i) { sden += alf(DenRes + i); snum += alf(NumRes + i); }
          out[0] = -(snum - sden);
        }
      }
    }
  } else {
    // ================= NUM (fully block-local) =================
    const int b = bid - NBD;
    float* qn   = (float*)smem;               // [2][256] 2 KB
    float* redn = (float*)(smem + 2048);      // [16][256] 16 KB
    float* Ms2  = (float*)(smem + 18432);     // [2]
    const size_t inb = (size_t)b * T_ * P_;
    const int slen = seqlen[b];

    // W regs: wn[kk*4+cc] = exp(trans[16*wv+kk][ln+64*cc])
    float wn[64];
    {
      const float* wb = num_trans + (size_t)(wv * 16) * SN_ + ln;
      #pragma unroll
      for (int kk = 0; kk < 16; ++kk) {
        #pragma unroll
        for (int cc = 0; cc < 4; ++cc)
          wn[kk * 4 + cc] = __expf(wb[(size_t)kk * SN_ + 64 * cc]);
      }
    }
    int pdfn[4] = {0, 0, 0, 0};
    float Lr = 0.f;
    if (wv == 0) {
      #pragma unroll
      for (int cc = 0; cc < 4; ++cc) pdfn[cc] = num_pdf[ln + 64 * cc];
      // init q(0), parity 0
      float mx = 0.f;
      #pragma unroll
      for (int cc = 0; cc < 4; ++cc) {
        const float v = __expf(num_init[ln + 64 * cc] + input[inb + pdfn[cc]]);
        qn[ln + 64 * cc] = v;
        mx = fmaxf(mx, v);
      }
      #pragma unroll
      for (int d = 1; d < 64; d <<= 1) mx = fmaxf(mx, __shfl_xor(mx, d));
      if (ln == 0) Ms2[0] = mx;
    }
    __syncthreads();

    int tlast = 0;
    for (int t = 1; t <= 511; ++t) {
      if (t >= slen) break;      // uniform per block
      tlast = t;
      const int pr = (t - 1) & 1, pw = t & 1;
      float e[4] = {0.f, 0.f, 0.f, 0.f};
      if (wv == 0) {
        #pragma unroll
        for (int cc = 0; cc < 4; ++cc) e[cc] = input[inb + (size_t)t * P_ + pdfn[cc]];
      }
      // compute: 4 cols {ln,+64,+128,+192} x k-slice [16*wv, 16*wv+16)
      const float* qp = qn + pr * 256 + wv * 16;
      float ac[4] = {0.f, 0.f, 0.f, 0.f};
      #pragma unroll
      for (int jj = 0; jj < 4; ++jj) {
        const float4 f = *(const float4*)(qp + 4 * jj);
        #pragma unroll
        for (int cc = 0; cc < 4; ++cc) {
          ac[cc] = fmaf(f.x, wn[(4*jj+0)*4+cc], ac[cc]);
          ac[cc] = fmaf(f.y, wn[(4*jj+1)*4+cc], ac[cc]);
          ac[cc] = fmaf(f.z, wn[(4*jj+2)*4+cc], ac[cc]);
          ac[cc] = fmaf(f.w, wn[(4*jj+3)*4+cc], ac[cc]);
        }
      }
      #pragma unroll
      for (int cc = 0; cc < 4; ++cc) redn[wv * 256 + cc * 64 + ln] = ac[cc];
      __syncthreads();
      if (wv == 0) {
        float acc[4] = {0.f, 0.f, 0.f, 0.f};
        #pragma unroll
        for (int w = 0; w < 16; ++w) {
          #pragma unroll
          for (int cc = 0; cc < 4; ++cc) acc[cc] += redn[w * 256 + cc * 64 + ln];
        }
        const float Mv = Ms2[pr];
        const float rM = 1.0f / Mv;
        float mx = 0.f;
        #pragma unroll
        for (int cc = 0; cc < 4; ++cc) {
          const float v = acc[cc] * rM * __expf(e[cc]);
          qn[pw * 256 + ln + 64 * cc] = v;
          mx = fmaxf(mx, v);
        }
        #pragma unroll
        for (int d = 1; d < 64; d <<= 1) mx = fmaxf(mx, __shfl_xor(mx, d));
        if (ln == 0) { Ms2[pw] = mx; Lr += __logf(Mv); }
      }
      __syncthreads();
    }
    // epilogue: wave-0 shuffle reduction of q(tlast) * exp(final)
    const int cur = tlast & 1;
    if (wv == 0) {
      float s = 0.f;
      #pragma unroll
      for (int cc = 0; cc < 4; ++cc)
        s += qn[cur * 256 + ln + 64 * cc] * __expf(num_final[ln + 64 * cc]);
      #pragma unroll
      for (int d = 1; d < 64; d <<= 1) s += __shfl_xor(s, d);
      if (ln == 0) {
        asf(NumRes + b, Lr + __logf(s));
        rsu(NF + b * 16, 0x600D0100u | (unsigned)b);
      }
    }
  }
}

extern "C" void kernel_launch(void* const* d_in, const int* in_sizes, int n_in,
                              void* d_out, int out_size, void* d_ws, size_t ws_size,
                              hipStream_t stream) {
  const float* input     = (const float*)d_in[0];
  const int*   seqlen    = (const int*)  d_in[1];
  const float* num_init  = (const float*)d_in[2];
  const float* num_trans = (const float*)d_in[3];
  const float* num_final = (const float*)d_in[4];
  const int*   num_pdf   = (const int*)  d_in[5];
  const float* den_init  = (const float*)d_in[6];
  const float* den_trans = (const float*)d_in[7];
  const float* den_final = (const float*)d_in[8];
  const int*   den_pdf   = (const int*)  d_in[9];
  float* out = (float*)d_out;
  float* ws  = (float*)d_ws;   // ~185 KB used (chunks + flags + results)

  void* args[] = { &input, &seqlen, &num_init, &num_trans, &num_final, &num_pdf,
                   &den_init, &den_trans, &den_final, &den_pdf, &out, &ws };
  hipLaunchCooperativeKernel((void*)lfmmi_kernel, dim3(NBLK), dim3(NTHR),
                             args, 0, stream);
}

// Round 6
// 5175.021 us; speedup vs baseline: 1.0133x; 1.0133x over previous
//
#include <hip/hip_runtime.h>

#define AG __HIP_MEMORY_SCOPE_AGENT
#define B_ 16
#define T_ 512
#define P_ 2048
#define SN_ 256
#define SD_ 1024
#define NGD 8                 // den groups (one b-pair each)
#define GB 16                 // blocks per den group (64 cols each)
#define NBD (NGD * GB)        // 128 den blocks
#define NBLK (NBD + B_)       // + 16 num blocks = 144
#define NTHR 1024
#define CHS 160               // chunk stride in floats (128 data + 2 M + pad)

__device__ __forceinline__ float alf(const float* p){ return __hip_atomic_load(p, __ATOMIC_RELAXED, AG); }
__device__ __forceinline__ void  asf(float* p, float v){ __hip_atomic_store(p, v, __ATOMIC_RELAXED, AG); }
__device__ __forceinline__ void  rsu(unsigned* p, unsigned v){ __hip_atomic_store(p, v, __ATOMIC_RELEASE, AG); }
__device__ __forceinline__ void wait_eq(unsigned* p, unsigned v){
  while (__hip_atomic_load(p, __ATOMIC_RELAXED, AG) != v) __builtin_amdgcn_s_sleep(1);
  asm volatile("" ::: "memory");   // keep data loads after the flag match
}

// Exp-space forward recursion, producer/consumer dataflow (no grid barrier):
//   q_t[b,c] = (sum_k q_{t-1}[b,k] * W[k,c]) / M[b] * exp(e_t[b,c])
// den: 8 groups x 16 blocks; group owns b-pair {2g,2g+1}; block owns 64 cols.
// W lives in REGISTERS (64 fp32/thread, loaded once) — zero per-step W LDS.
// __launch_bounds__(1024, 4): min 4 waves/EU -> VGPR cap 128/thread. Round 5
// omitted the 2nd arg; compiler capped at 64 VGPRs and SPILLED W to scratch
// (VGPR_Count=64, VALUBusy 5%, FETCH +130MB). This line is the whole fix.
// Exchange: 512B chunk + epoch flag (exact-match), 2 parities; publish and
// release all from wave 0 (release store orders wave-0 stores -> no sync).
// num: fully block-local, W in registers, 16 independent blocks.
__global__ __launch_bounds__(NTHR, 4) void lfmmi_kernel(
    const float* __restrict__ input, const int* __restrict__ seqlen,
    const float* __restrict__ num_init, const float* __restrict__ num_trans,
    const float* __restrict__ num_final, const int* __restrict__ num_pdf,
    const float* __restrict__ den_init, const float* __restrict__ den_trans,
    const float* __restrict__ den_final, const int* __restrict__ den_pdf,
    float* __restrict__ out, float* __restrict__ ws)
{
  __shared__ __align__(16) unsigned char smem[24832];
  const int tid = threadIdx.x;
  const int bid = blockIdx.x;

  // workspace carve
  float*    Qc     = ws;                               // [2][NGD][GB][CHS]
  unsigned* F      = (unsigned*)(Qc + 2*NGD*GB*CHS);   // [2][NGD][GB][16]
  float*    DenRes = (float*)(F + 2*NGD*GB*16);        // [16]
  float*    NumRes = DenRes + 16;                      // [16]
  unsigned* DF     = (unsigned*)(NumRes + 16);         // [NGD][16]
  unsigned* NF     = DF + NGD*16;                      // [16][16]

  const int wv = tid >> 6, ln = tid & 63;

  if (bid < NBD) {
    // ================= DEN =================
    const int g = bid >> 4, r = bid & 15;
    const int cg = tid & 31, kq = tid >> 5;   // tile: cols {cg, cg+32}, k-slice 32
    const int col0 = r * 64;

    float* qs    = (float*)smem;              // [2][2][1024] 16 KB (parity,b,col)
    float2* red2 = (float2*)(smem + 16384);   // [16][64] 8 KB
    float* Ms    = (float*)(smem + 24576);    // [2][2] (parity, b)

    // --- W into registers: wA/wB[kk] = exp(trans[kq*32+kk][col0+cg(+32)]) ---
    float wA[32], wB[32];
    {
      const float* wb = den_trans + (size_t)(kq * 32) * SD_ + col0 + cg;
      #pragma unroll
      for (int kk = 0; kk < 32; ++kk) {
        wA[kk] = __expf(wb[(size_t)kk * SD_]);
        wB[kk] = __expf(wb[(size_t)kk * SD_ + 32]);
      }
    }

    const int b0 = 2 * g, b1 = 2 * g + 1;
    const int slen0 = seqlen[b0], slen1 = seqlen[b1];
    const size_t inb0 = (size_t)b0 * T_ * P_, inb1 = (size_t)b1 * T_ * P_;
    int pdf0 = 0;
    if (wv == 0) pdf0 = den_pdf[col0 + ln];

    // --- init publish (t=0, parity 0) — wave 0 only ---
    if (wv == 0) {
      float* ch0 = Qc + ((size_t)(0 * NGD + g) * GB + r) * CHS;
      const float v0 = __expf(den_init[col0 + ln] + input[inb0 + pdf0]);
      const float v1 = __expf(den_init[col0 + ln] + input[inb1 + pdf0]);
      asf(ch0 + ln, v0); asf(ch0 + 64 + ln, v1);
      if (r == 0) {
        float m0 = v0, m1 = v1;
        #pragma unroll
        for (int d = 1; d < 64; d <<= 1) {
          m0 = fmaxf(m0, __shfl_xor(m0, d));
          m1 = fmaxf(m1, __shfl_xor(m1, d));
        }
        if (ln == 0) { asf(ch0 + 128, m0); asf(ch0 + 129, m1); }
      }
      if (tid == 0) rsu(F + ((0 * NGD + g) * GB + r) * 16, 0u);  // orders wave-0 stores
    }

    float Lr0 = 0.f, Lr1 = 0.f;
    for (int t = 1; t <= 511; ++t) {
      const int pp = (t - 1) & 1, pc = t & 1;
      float e0 = 0.f, e1 = 0.f;
      if (wv == 0) {   // emission gather prefetch (unconditional; hidden by compute)
        e0 = input[inb0 + (size_t)t * P_ + pdf0];
        e1 = input[inb1 + (size_t)t * P_ + pdf0];
      }
      // stage q_{t-1}: wave wv polls producer wv's flag, loads its chunk
      wait_eq(F + ((pp * NGD + g) * GB + wv) * 16, (unsigned)(t - 1));
      {
        const float* ch = Qc + ((size_t)(pp * NGD + g) * GB + wv) * CHS;
        qs[pp * 2048 + wv * 64 + ln]        = alf(ch + ln);
        qs[pp * 2048 + 1024 + wv * 64 + ln] = alf(ch + 64 + ln);
        if (wv == 0 && ln < 2) Ms[pp * 2 + ln] = alf(ch + 128 + ln);
      }
      __syncthreads();
      // compute 2c x 2b tile over k-slice 32; q via half-wave LDS broadcast
      const float* q0 = qs + pp * 2048 + kq * 32;
      const float* q1 = q0 + 1024;
      float a00 = 0.f, a01 = 0.f, a10 = 0.f, a11 = 0.f;
      #pragma unroll
      for (int jj = 0; jj < 8; ++jj) {
        const float4 f0 = *(const float4*)(q0 + 4 * jj);
        const float4 f1 = *(const float4*)(q1 + 4 * jj);
        a00 = fmaf(f0.x, wA[4*jj+0], a00); a00 = fmaf(f0.y, wA[4*jj+1], a00);
        a00 = fmaf(f0.z, wA[4*jj+2], a00); a00 = fmaf(f0.w, wA[4*jj+3], a00);
        a01 = fmaf(f0.x, wB[4*jj+0], a01); a01 = fmaf(f0.y, wB[4*jj+1], a01);
        a01 = fmaf(f0.z, wB[4*jj+2], a01); a01 = fmaf(f0.w, wB[4*jj+3], a01);
        a10 = fmaf(f1.x, wA[4*jj+0], a10); a10 = fmaf(f1.y, wA[4*jj+1], a10);
        a10 = fmaf(f1.z, wA[4*jj+2], a10); a10 = fmaf(f1.w, wA[4*jj+3], a10);
        a11 = fmaf(f1.x, wB[4*jj+0], a11); a11 = fmaf(f1.y, wB[4*jj+1], a11);
        a11 = fmaf(f1.z, wB[4*jj+2], a11); a11 = fmaf(f1.w, wB[4*jj+3], a11);
      }
      a00 += __shfl_xor(a00, 32); a01 += __shfl_xor(a01, 32);
      a10 += __shfl_xor(a10, 32); a11 += __shfl_xor(a11, 32);
      if (ln < 32) {
        red2[wv * 64 + cg]      = make_float2(a00, a10);
        red2[wv * 64 + 32 + cg] = make_float2(a01, a11);
      }
      __syncthreads();
      // wave 0: fold 16 partials, scale, publish, release (no extra sync)
      if (wv == 0) {
        float acc0 = 0.f, acc1 = 0.f;
        #pragma unroll
        for (int w = 0; w < 16; ++w) {
          const float2 v = red2[w * 64 + ln];
          acc0 += v.x; acc1 += v.y;
        }
        const float Mv0 = Ms[pp * 2 + 0], Mv1 = Ms[pp * 2 + 1];
        const float v0 = (t < slen0) ? (acc0 / Mv0) * __expf(e0)
                                     : qs[pp * 2048 + col0 + ln];
        const float v1 = (t < slen1) ? (acc1 / Mv1) * __expf(e1)
                                     : qs[pp * 2048 + 1024 + col0 + ln];
        float* ch = Qc + ((size_t)(pc * NGD + g) * GB + r) * CHS;
        asf(ch + ln, v0); asf(ch + 64 + ln, v1);
        if (r == 0) {
          float m0 = v0, m1 = v1;
          #pragma unroll
          for (int d = 1; d < 64; d <<= 1) {
            m0 = fmaxf(m0, __shfl_xor(m0, d));
            m1 = fmaxf(m1, __shfl_xor(m1, d));
          }
          if (ln == 0) {
            asf(ch + 128, m0); asf(ch + 129, m1);
            if (t < slen0) Lr0 += __logf(Mv0);
            if (t < slen1) Lr1 += __logf(Mv1);
          }
        }
        if (tid == 0) rsu(F + ((pc * NGD + g) * GB + r) * 16, (unsigned)t);
      }
    }

    // --- epilogue: r==0 blocks reduce final q (t=511, parity 1) ---
    if (r == 0) {
      wait_eq(F + ((1 * NGD + g) * GB + wv) * 16, 511u);
      {
        const float* ch = Qc + ((size_t)(1 * NGD + g) * GB + wv) * CHS;
        qs[2048 + wv * 64 + ln]        = alf(ch + ln);        // parity-1 region:
        qs[2048 + 1024 + wv * 64 + ln] = alf(ch + 64 + ln);   // avoids fold's carry reads
      }
      __syncthreads();
      float* red = (float*)red2;   // 2048 floats
      const int b2e = tid >> 9, ce = tid & 511;
      red[tid] = qs[2048 + b2e * 1024 + ce] * __expf(den_final[ce])
               + qs[2048 + b2e * 1024 + 512 + ce] * __expf(den_final[512 + ce]);
      __syncthreads();
      for (int off = 256; off; off >>= 1) {
        const int base = (tid >= 512) ? 512 : 0, i = tid - base;
        if (i < off) red[base + i] += red[base + i + off];
        __syncthreads();
      }
      if (tid == 0) {
        asf(DenRes + 2 * g,     Lr0 + __logf(red[0]));
        asf(DenRes + 2 * g + 1, Lr1 + __logf(red[512]));
        rsu(DF + g * 16, 0x600D0000u | (unsigned)g);
        if (g == 0) {
          for (int g2 = 0; g2 < NGD; ++g2) wait_eq(DF + g2 * 16, 0x600D0000u | (unsigned)g2);
          for (int b2 = 0; b2 < B_; ++b2)  wait_eq(NF + b2 * 16, 0x600D0100u | (unsigned)b2);
          float sden = 0.f, snum = 0.f;
          for (int i = 0; i < 16; ++i) { sden += alf(DenRes + i); snum += alf(NumRes + i); }
          out[0] = -(snum - sden);
        }
      }
    }
  } else {
    // ================= NUM (fully block-local) =================
    const int b = bid - NBD;
    float* qn   = (float*)smem;               // [2][256] 2 KB
    float* redn = (float*)(smem + 2048);      // [16][256] 16 KB
    float* Ms2  = (float*)(smem + 18432);     // [2]
    const size_t inb = (size_t)b * T_ * P_;
    const int slen = seqlen[b];

    // W regs: wn[kk*4+cc] = exp(trans[16*wv+kk][ln+64*cc])
    float wn[64];
    {
      const float* wb = num_trans + (size_t)(wv * 16) * SN_ + ln;
      #pragma unroll
      for (int kk = 0; kk < 16; ++kk) {
        #pragma unroll
        for (int cc = 0; cc < 4; ++cc)
          wn[kk * 4 + cc] = __expf(wb[(size_t)kk * SN_ + 64 * cc]);
      }
    }
    int pdfn[4] = {0, 0, 0, 0};
    float Lr = 0.f;
    if (wv == 0) {
      #pragma unroll
      for (int cc = 0; cc < 4; ++cc) pdfn[cc] = num_pdf[ln + 64 * cc];
      // init q(0), parity 0
      float mx = 0.f;
      #pragma unroll
      for (int cc = 0; cc < 4; ++cc) {
        const float v = __expf(num_init[ln + 64 * cc] + input[inb + pdfn[cc]]);
        qn[ln + 64 * cc] = v;
        mx = fmaxf(mx, v);
      }
      #pragma unroll
      for (int d = 1; d < 64; d <<= 1) mx = fmaxf(mx, __shfl_xor(mx, d));
      if (ln == 0) Ms2[0] = mx;
    }
    __syncthreads();

    int tlast = 0;
    for (int t = 1; t <= 511; ++t) {
      if (t >= slen) break;      // uniform per block
      tlast = t;
      const int pr = (t - 1) & 1, pw = t & 1;
      float e[4] = {0.f, 0.f, 0.f, 0.f};
      if (wv == 0) {
        #pragma unroll
        for (int cc = 0; cc < 4; ++cc) e[cc] = input[inb + (size_t)t * P_ + pdfn[cc]];
      }
      // compute: 4 cols {ln,+64,+128,+192} x k-slice [16*wv, 16*wv+16)
      const float* qp = qn + pr * 256 + wv * 16;
      float ac[4] = {0.f, 0.f, 0.f, 0.f};
      #pragma unroll
      for (int jj = 0; jj < 4; ++jj) {
        const float4 f = *(const float4*)(qp + 4 * jj);
        #pragma unroll
        for (int cc = 0; cc < 4; ++cc) {
          ac[cc] = fmaf(f.x, wn[(4*jj+0)*4+cc], ac[cc]);
          ac[cc] = fmaf(f.y, wn[(4*jj+1)*4+cc], ac[cc]);
          ac[cc] = fmaf(f.z, wn[(4*jj+2)*4+cc], ac[cc]);
          ac[cc] = fmaf(f.w, wn[(4*jj+3)*4+cc], ac[cc]);
        }
      }
      #pragma unroll
      for (int cc = 0; cc < 4; ++cc) redn[wv * 256 + cc * 64 + ln] = ac[cc];
      __syncthreads();
      if (wv == 0) {
        float acc[4] = {0.f, 0.f, 0.f, 0.f};
        #pragma unroll
        for (int w = 0; w < 16; ++w) {
          #pragma unroll
          for (int cc = 0; cc < 4; ++cc) acc[cc] += redn[w * 256 + cc * 64 + ln];
        }
        const float Mv = Ms2[pr];
        const float rM = 1.0f / Mv;
        float mx = 0.f;
        #pragma unroll
        for (int cc = 0; cc < 4; ++cc) {
          const float v = acc[cc] * rM * __expf(e[cc]);
          qn[pw * 256 + ln + 64 * cc] = v;
          mx = fmaxf(mx, v);
        }
        #pragma unroll
        for (int d = 1; d < 64; d <<= 1) mx = fmaxf(mx, __shfl_xor(mx, d));
        if (ln == 0) { Ms2[pw] = mx; Lr += __logf(Mv); }
      }
      __syncthreads();
    }
    // epilogue: wave-0 shuffle reduction of q(tlast) * exp(final)
    const int cur = tlast & 1;
    if (wv == 0) {
      float s = 0.f;
      #pragma unroll
      for (int cc = 0; cc < 4; ++cc)
        s += qn[cur * 256 + ln + 64 * cc] * __expf(num_final[ln + 64 * cc]);
      #pragma unroll
      for (int d = 1; d < 64; d <<= 1) s += __shfl_xor(s, d);
      if (ln == 0) {
        asf(NumRes + b, Lr + __logf(s));
        rsu(NF + b * 16, 0x600D0100u | (unsigned)b);
      }
    }
  }
}

extern "C" void kernel_launch(void* const* d_in, const int* in_sizes, int n_in,
                              void* d_out, int out_size, void* d_ws, size_t ws_size,
                              hipStream_t stream) {
  const float* input     = (const float*)d_in[0];
  const int*   seqlen    = (const int*)  d_in[1];
  const float* num_init  = (const float*)d_in[2];
  const float* num_trans = (const float*)d_in[3];
  const float* num_final = (const float*)d_in[4];
  const int*   num_pdf   = (const int*)  d_in[5];
  const float* den_init  = (const float*)d_in[6];
  const float* den_trans = (const float*)d_in[7];
  const float* den_final = (const float*)d_in[8];
  const int*   den_pdf   = (const int*)  d_in[9];
  float* out = (float*)d_out;
  float* ws  = (float*)d_ws;   // ~185 KB used (chunks + flags + results)

  void* args[] = { &input, &seqlen, &num_init, &num_trans, &num_final, &num_pdf,
                   &den_init, &den_trans, &den_final, &den_pdf, &out, &ws };
  hipLaunchCooperativeKernel((void*)lfmmi_kernel, dim3(NBLK), dim3(NTHR),
                             args, 0, stream);
}

// Round 7
// 2410.295 us; speedup vs baseline: 2.1756x; 2.1470x over previous
//
#include <hip/hip_runtime.h>

#define AG __HIP_MEMORY_SCOPE_AGENT
#define B_ 16
#define T_ 512
#define P_ 2048
#define SN_ 256
#define SD_ 1024
#define NGD 8                 // den groups (one b-pair each)
#define GB 16                 // blocks per den group (64 cols each)
#define NBD (NGD * GB)        // 128 den blocks
#define NBLK (NBD + B_)       // + 16 num blocks = 144
#define NTHR 1024
#define CHS 160               // chunk stride in floats (128 data + 2 M + pad)

__device__ __forceinline__ float alf(const float* p){ return __hip_atomic_load(p, __ATOMIC_RELAXED, AG); }
__device__ __forceinline__ void  asf(float* p, float v){ __hip_atomic_store(p, v, __ATOMIC_RELAXED, AG); }
__device__ __forceinline__ void  rsu(unsigned* p, unsigned v){ __hip_atomic_store(p, v, __ATOMIC_RELEASE, AG); }
__device__ __forceinline__ void wait_eq(unsigned* p, unsigned v){
  while (__hip_atomic_load(p, __ATOMIC_RELAXED, AG) != v) __builtin_amdgcn_s_sleep(1);
  asm volatile("" ::: "memory");   // keep data loads after the flag match
}

// Exp-space forward recursion, producer/consumer dataflow (no grid barrier):
//   q_t[b,c] = (sum_k q_{t-1}[b,k] * W[k,c]) / M[b] * exp(e_t[b,c])
// den: 8 groups x 16 blocks; group owns b-pair {2g,2g+1}; block owns 64 cols.
// W lives in REGISTERS (64 fp32/thread, loaded once) — zero per-step W LDS.
//
// amdgpu_waves_per_eu(4,4): pins occupancy to 4 waves/EU -> allocator budget
// 512/4 = 128 VGPRs. Rounds 5/6 proved __launch_bounds__(1024,4) leaves the
// cap at 64 (VGPR_Count=64, W spilled to scratch, VALUBusy 5%). This LLVM
// attribute has min=max semantics, no CUDA translation ambiguity.
//
// Exchange: 512B chunk + epoch flag (exact-match), 2 parities; publish and
// release all from wave 0 (release store orders wave-0 stores -> no sync).
// Partial sums in two scalar arrays (4B stride) -> conflict-free fold reads
// (round 5/6's float2 fold was 4-way bank-aliased: 3.56M conflict cycles).
// num: fully block-local, W in registers, 16 independent blocks.
__global__ void __attribute__((amdgpu_flat_work_group_size(1024, 1024)))
__attribute__((amdgpu_waves_per_eu(4, 4))) lfmmi_kernel(
    const float* __restrict__ input, const int* __restrict__ seqlen,
    const float* __restrict__ num_init, const float* __restrict__ num_trans,
    const float* __restrict__ num_final, const int* __restrict__ num_pdf,
    const float* __restrict__ den_init, const float* __restrict__ den_trans,
    const float* __restrict__ den_final, const int* __restrict__ den_pdf,
    float* __restrict__ out, float* __restrict__ ws)
{
  __shared__ __align__(16) unsigned char smem[24832];
  const int tid = threadIdx.x;
  const int bid = blockIdx.x;

  // workspace carve
  float*    Qc     = ws;                               // [2][NGD][GB][CHS]
  unsigned* F      = (unsigned*)(Qc + 2*NGD*GB*CHS);   // [2][NGD][GB][16]
  float*    DenRes = (float*)(F + 2*NGD*GB*16);        // [16]
  float*    NumRes = DenRes + 16;                      // [16]
  unsigned* DF     = (unsigned*)(NumRes + 16);         // [NGD][16]
  unsigned* NF     = DF + NGD*16;                      // [16][16]

  const int wv = tid >> 6, ln = tid & 63;

  if (bid < NBD) {
    // ================= DEN =================
    const int g = bid >> 4, r = bid & 15;
    const int cg = tid & 31, kq = tid >> 5;   // tile: cols {cg, cg+32}, k-slice 32
    const int col0 = r * 64;

    float* qs   = (float*)smem;               // [2][2][1024] 16 KB (parity,b,col)
    float* redA = (float*)(smem + 16384);     // [16][64] b0 partials, 4 KB
    float* redB = redA + 1024;                // [16][64] b1 partials, 4 KB
    float* Ms   = (float*)(smem + 24576);     // [2][2] (parity, b)

    // --- W into registers: wA/wB[kk] = exp(trans[kq*32+kk][col0+cg(+32)]) ---
    float wA[32], wB[32];
    {
      const float* wb = den_trans + (size_t)(kq * 32) * SD_ + col0 + cg;
      #pragma unroll
      for (int kk = 0; kk < 32; ++kk) {
        wA[kk] = __expf(wb[(size_t)kk * SD_]);
        wB[kk] = __expf(wb[(size_t)kk * SD_ + 32]);
      }
    }

    const int b0 = 2 * g, b1 = 2 * g + 1;
    const int slen0 = seqlen[b0], slen1 = seqlen[b1];
    const size_t inb0 = (size_t)b0 * T_ * P_, inb1 = (size_t)b1 * T_ * P_;
    int pdf0 = 0;
    if (wv == 0) pdf0 = den_pdf[col0 + ln];

    // --- init publish (t=0, parity 0) — wave 0 only ---
    if (wv == 0) {
      float* ch0 = Qc + ((size_t)(0 * NGD + g) * GB + r) * CHS;
      const float v0 = __expf(den_init[col0 + ln] + input[inb0 + pdf0]);
      const float v1 = __expf(den_init[col0 + ln] + input[inb1 + pdf0]);
      asf(ch0 + ln, v0); asf(ch0 + 64 + ln, v1);
      if (r == 0) {
        float m0 = v0, m1 = v1;
        #pragma unroll
        for (int d = 1; d < 64; d <<= 1) {
          m0 = fmaxf(m0, __shfl_xor(m0, d));
          m1 = fmaxf(m1, __shfl_xor(m1, d));
        }
        if (ln == 0) { asf(ch0 + 128, m0); asf(ch0 + 129, m1); }
      }
      if (tid == 0) rsu(F + ((0 * NGD + g) * GB + r) * 16, 0u);  // orders wave-0 stores
    }

    float Lr0 = 0.f, Lr1 = 0.f;
    for (int t = 1; t <= 511; ++t) {
      const int pp = (t - 1) & 1, pc = t & 1;
      float e0 = 0.f, e1 = 0.f;
      if (wv == 0) {   // emission gather prefetch (unconditional; hidden by compute)
        e0 = input[inb0 + (size_t)t * P_ + pdf0];
        e1 = input[inb1 + (size_t)t * P_ + pdf0];
      }
      // stage q_{t-1}: wave wv polls producer wv's flag, loads its chunk
      wait_eq(F + ((pp * NGD + g) * GB + wv) * 16, (unsigned)(t - 1));
      {
        const float* ch = Qc + ((size_t)(pp * NGD + g) * GB + wv) * CHS;
        qs[pp * 2048 + wv * 64 + ln]        = alf(ch + ln);
        qs[pp * 2048 + 1024 + wv * 64 + ln] = alf(ch + 64 + ln);
        if (wv == 0 && ln < 2) Ms[pp * 2 + ln] = alf(ch + 128 + ln);
      }
      __syncthreads();
      // compute 2c x 2b tile over k-slice 32; q via half-wave LDS broadcast
      const float* q0 = qs + pp * 2048 + kq * 32;
      const float* q1 = q0 + 1024;
      float a00 = 0.f, a01 = 0.f, a10 = 0.f, a11 = 0.f;
      #pragma unroll
      for (int jj = 0; jj < 8; ++jj) {
        const float4 f0 = *(const float4*)(q0 + 4 * jj);
        const float4 f1 = *(const float4*)(q1 + 4 * jj);
        a00 = fmaf(f0.x, wA[4*jj+0], a00); a00 = fmaf(f0.y, wA[4*jj+1], a00);
        a00 = fmaf(f0.z, wA[4*jj+2], a00); a00 = fmaf(f0.w, wA[4*jj+3], a00);
        a01 = fmaf(f0.x, wB[4*jj+0], a01); a01 = fmaf(f0.y, wB[4*jj+1], a01);
        a01 = fmaf(f0.z, wB[4*jj+2], a01); a01 = fmaf(f0.w, wB[4*jj+3], a01);
        a10 = fmaf(f1.x, wA[4*jj+0], a10); a10 = fmaf(f1.y, wA[4*jj+1], a10);
        a10 = fmaf(f1.z, wA[4*jj+2], a10); a10 = fmaf(f1.w, wA[4*jj+3], a10);
        a11 = fmaf(f1.x, wB[4*jj+0], a11); a11 = fmaf(f1.y, wB[4*jj+1], a11);
        a11 = fmaf(f1.z, wB[4*jj+2], a11); a11 = fmaf(f1.w, wB[4*jj+3], a11);
      }
      a00 += __shfl_xor(a00, 32); a01 += __shfl_xor(a01, 32);
      a10 += __shfl_xor(a10, 32); a11 += __shfl_xor(a11, 32);
      if (ln < 32) {   // 4B-stride scalar writes: conflict-free
        redA[wv * 64 + cg] = a00; redA[wv * 64 + 32 + cg] = a01;
        redB[wv * 64 + cg] = a10; redB[wv * 64 + 32 + cg] = a11;
      }
      __syncthreads();
      // wave 0: fold 16 partials (4B-stride reads, conflict-free), publish
      if (wv == 0) {
        float acc0 = 0.f, acc1 = 0.f;
        #pragma unroll
        for (int w = 0; w < 16; ++w) {
          acc0 += redA[w * 64 + ln];
          acc1 += redB[w * 64 + ln];
        }
        const float Mv0 = Ms[pp * 2 + 0], Mv1 = Ms[pp * 2 + 1];
        const float v0 = (t < slen0) ? (acc0 / Mv0) * __expf(e0)
                                     : qs[pp * 2048 + col0 + ln];
        const float v1 = (t < slen1) ? (acc1 / Mv1) * __expf(e1)
                                     : qs[pp * 2048 + 1024 + col0 + ln];
        float* ch = Qc + ((size_t)(pc * NGD + g) * GB + r) * CHS;
        asf(ch + ln, v0); asf(ch + 64 + ln, v1);
        if (r == 0) {
          float m0 = v0, m1 = v1;
          #pragma unroll
          for (int d = 1; d < 64; d <<= 1) {
            m0 = fmaxf(m0, __shfl_xor(m0, d));
            m1 = fmaxf(m1, __shfl_xor(m1, d));
          }
          if (ln == 0) {
            asf(ch + 128, m0); asf(ch + 129, m1);
            if (t < slen0) Lr0 += __logf(Mv0);
            if (t < slen1) Lr1 += __logf(Mv1);
          }
        }
        if (tid == 0) rsu(F + ((pc * NGD + g) * GB + r) * 16, (unsigned)t);
      }
    }

    // --- epilogue: r==0 blocks reduce final q (t=511, parity 1) ---
    if (r == 0) {
      wait_eq(F + ((1 * NGD + g) * GB + wv) * 16, 511u);
      {
        const float* ch = Qc + ((size_t)(1 * NGD + g) * GB + wv) * CHS;
        qs[2048 + wv * 64 + ln]        = alf(ch + ln);        // parity-1 region:
        qs[2048 + 1024 + wv * 64 + ln] = alf(ch + 64 + ln);   // avoids fold's carry reads
      }
      __syncthreads();
      float* red = redA;   // redA+redB = 2048 contiguous floats
      const int b2e = tid >> 9, ce = tid & 511;
      red[tid] = qs[2048 + b2e * 1024 + ce] * __expf(den_final[ce])
               + qs[2048 + b2e * 1024 + 512 + ce] * __expf(den_final[512 + ce]);
      __syncthreads();
      for (int off = 256; off; off >>= 1) {
        const int base = (tid >= 512) ? 512 : 0, i = tid - base;
        if (i < off) red[base + i] += red[base + i + off];
        __syncthreads();
      }
      if (tid == 0) {
        asf(DenRes + 2 * g,     Lr0 + __logf(red[0]));
        asf(DenRes + 2 * g + 1, Lr1 + __logf(red[512]));
        rsu(DF + g * 16, 0x600D0000u | (unsigned)g);
        if (g == 0) {
          for (int g2 = 0; g2 < NGD; ++g2) wait_eq(DF + g2 * 16, 0x600D0000u | (unsigned)g2);
          for (int b2 = 0; b2 < B_; ++b2)  wait_eq(NF + b2 * 16, 0x600D0100u | (unsigned)b2);
          float sden = 0.f, snum = 0.f;
          for (int i = 0; i < 16; ++i) { sden += alf(DenRes + i); snum += alf(NumRes + i); }
          out[0] = -(snum - sden);
        }
      }
    }
  } else {
    // ================= NUM (fully block-local) =================
    const int b = bid - NBD;
    float* qn   = (float*)smem;               // [2][256] 2 KB
    float* redn = (float*)(smem + 2048);      // [16][256] 16 KB
    float* Ms2  = (float*)(smem + 18432);     // [2]
    const size_t inb = (size_t)b * T_ * P_;
    const int slen = seqlen[b];

    // W regs: wn[kk*4+cc] = exp(trans[16*wv+kk][ln+64*cc])
    float wn[64];
    {
      const float* wb = num_trans + (size_t)(wv * 16) * SN_ + ln;
      #pragma unroll
      for (int kk = 0; kk < 16; ++kk) {
        #pragma unroll
        for (int cc = 0; cc < 4; ++cc)
          wn[kk * 4 + cc] = __expf(wb[(size_t)kk * SN_ + 64 * cc]);
      }
    }
    int pdfn[4] = {0, 0, 0, 0};
    float Lr = 0.f;
    if (wv == 0) {
      #pragma unroll
      for (int cc = 0; cc < 4; ++cc) pdfn[cc] = num_pdf[ln + 64 * cc];
      // init q(0), parity 0
      float mx = 0.f;
      #pragma unroll
      for (int cc = 0; cc < 4; ++cc) {
        const float v = __expf(num_init[ln + 64 * cc] + input[inb + pdfn[cc]]);
        qn[ln + 64 * cc] = v;
        mx = fmaxf(mx, v);
      }
      #pragma unroll
      for (int d = 1; d < 64; d <<= 1) mx = fmaxf(mx, __shfl_xor(mx, d));
      if (ln == 0) Ms2[0] = mx;
    }
    __syncthreads();

    int tlast = 0;
    for (int t = 1; t <= 511; ++t) {
      if (t >= slen) break;      // uniform per block
      tlast = t;
      const int pr = (t - 1) & 1, pw = t & 1;
      float e[4] = {0.f, 0.f, 0.f, 0.f};
      if (wv == 0) {
        #pragma unroll
        for (int cc = 0; cc < 4; ++cc) e[cc] = input[inb + (size_t)t * P_ + pdfn[cc]];
      }
      // compute: 4 cols {ln,+64,+128,+192} x k-slice [16*wv, 16*wv+16)
      const float* qp = qn + pr * 256 + wv * 16;
      float ac[4] = {0.f, 0.f, 0.f, 0.f};
      #pragma unroll
      for (int jj = 0; jj < 4; ++jj) {
        const float4 f = *(const float4*)(qp + 4 * jj);
        #pragma unroll
        for (int cc = 0; cc < 4; ++cc) {
          ac[cc] = fmaf(f.x, wn[(4*jj+0)*4+cc], ac[cc]);
          ac[cc] = fmaf(f.y, wn[(4*jj+1)*4+cc], ac[cc]);
          ac[cc] = fmaf(f.z, wn[(4*jj+2)*4+cc], ac[cc]);
          ac[cc] = fmaf(f.w, wn[(4*jj+3)*4+cc], ac[cc]);
        }
      }
      #pragma unroll
      for (int cc = 0; cc < 4; ++cc) redn[wv * 256 + cc * 64 + ln] = ac[cc];
      __syncthreads();
      if (wv == 0) {
        float acc[4] = {0.f, 0.f, 0.f, 0.f};
        #pragma unroll
        for (int w = 0; w < 16; ++w) {
          #pragma unroll
          for (int cc = 0; cc < 4; ++cc) acc[cc] += redn[w * 256 + cc * 64 + ln];
        }
        const float Mv = Ms2[pr];
        const float rM = 1.0f / Mv;
        float mx = 0.f;
        #pragma unroll
        for (int cc = 0; cc < 4; ++cc) {
          const float v = acc[cc] * rM * __expf(e[cc]);
          qn[pw * 256 + ln + 64 * cc] = v;
          mx = fmaxf(mx, v);
        }
        #pragma unroll
        for (int d = 1; d < 64; d <<= 1) mx = fmaxf(mx, __shfl_xor(mx, d));
        if (ln == 0) { Ms2[pw] = mx; Lr += __logf(Mv); }
      }
      __syncthreads();
    }
    // epilogue: wave-0 shuffle reduction of q(tlast) * exp(final)
    const int cur = tlast & 1;
    if (wv == 0) {
      float s = 0.f;
      #pragma unroll
      for (int cc = 0; cc < 4; ++cc)
        s += qn[cur * 256 + ln + 64 * cc] * __expf(num_final[ln + 64 * cc]);
      #pragma unroll
      for (int d = 1; d < 64; d <<= 1) s += __shfl_xor(s, d);
      if (ln == 0) {
        asf(NumRes + b, Lr + __logf(s));
        rsu(NF + b * 16, 0x600D0100u | (unsigned)b);
      }
    }
  }
}

extern "C" void kernel_launch(void* const* d_in, const int* in_sizes, int n_in,
                              void* d_out, int out_size, void* d_ws, size_t ws_size,
                              hipStream_t stream) {
  const float* input     = (const float*)d_in[0];
  const int*   seqlen    = (const int*)  d_in[1];
  const float* num_init  = (const float*)d_in[2];
  const float* num_trans = (const float*)d_in[3];
  const float* num_final = (const float*)d_in[4];
  const int*   num_pdf   = (const int*)  d_in[5];
  const float* den_init  = (const float*)d_in[6];
  const float* den_trans = (const float*)d_in[7];
  const float* den_final = (const float*)d_in[8];
  const int*   den_pdf   = (const int*)  d_in[9];
  float* out = (float*)d_out;
  float* ws  = (float*)d_ws;   // ~185 KB used (chunks + flags + results)

  void* args[] = { &input, &seqlen, &num_init, &num_trans, &num_final, &num_pdf,
                   &den_init, &den_trans, &den_final, &den_pdf, &out, &ws };
  hipLaunchCooperativeKernel((void*)lfmmi_kernel, dim3(NBLK), dim3(NTHR),
                             args, 0, stream);
}

// Round 8
// 1492.762 us; speedup vs baseline: 3.5129x; 1.6147x over previous
//
#include <hip/hip_runtime.h>

#define AG __HIP_MEMORY_SCOPE_AGENT
#define B_ 16
#define T_ 512
#define P_ 2048
#define SN_ 256
#define SD_ 1024
#define NGD 8                 // den groups (one b-pair each)
#define GB 16                 // blocks per den group (64 cols each)
#define NBD (NGD * GB)        // 128 den blocks
#define NBLK (NBD + B_)       // + 16 num blocks = 144
#define NTHR 1024
#define CHU 136               // chunk stride in u64 (64 b0 + 64 b1 + 2 M + pad)

typedef unsigned long long u64;

__device__ __forceinline__ float alf(const float* p){ return __hip_atomic_load(p, __ATOMIC_RELAXED, AG); }
__device__ __forceinline__ void  asf(float* p, float v){ __hip_atomic_store(p, v, __ATOMIC_RELAXED, AG); }
__device__ __forceinline__ void  rsu(unsigned* p, unsigned v){ __hip_atomic_store(p, v, __ATOMIC_RELEASE, AG); }
__device__ __forceinline__ u64   ald64(const u64* p){ return __hip_atomic_load(p, __ATOMIC_RELAXED, AG); }
__device__ __forceinline__ void  ast64(u64* p, u64 v){ __hip_atomic_store(p, v, __ATOMIC_RELAXED, AG); }
__device__ __forceinline__ u64   pk(float v, unsigned t){ return ((u64)t << 32) | (u64)__float_as_uint(v); }
__device__ __forceinline__ void wait_eq(unsigned* p, unsigned v){
  while (__hip_atomic_load(p, __ATOMIC_RELAXED, AG) != v) __builtin_amdgcn_s_sleep(1);
  asm volatile("" ::: "memory");
}
// poll a tagged word until its epoch matches; payload rides in the same 8B —
// no separate flag->data round trip, no release ordering needed.
__device__ __forceinline__ float poll_tag(const u64* p, unsigned et){
  u64 x = ald64(p);
  while ((unsigned)(x >> 32) != et) x = ald64(p);
  return __uint_as_float((unsigned)x);
}

// Exp-space forward recursion, producer/consumer dataflow (no grid barrier):
//   q_t[b,c] = (sum_k q_{t-1}[b,k] * W[k,c]) / M[b] * exp(e_t[b,c])
// den: 8 groups x 16 blocks; group owns b-pair {2g,2g+1}; block owns 64 cols.
// W in registers (64 fp32/thread; gfx950 unified VGPR/AGPR file holds it —
// round 7 evidence: VGPR_Count=64 arch + AGPRs, no scratch symptoms).
// Exchange: each q value is a tagged u64 {epoch, fp32} stored relaxed agent
// scope. Consumer polls its own lane's words; tag match == data valid.
// 0xAA..A poison never matches tags [0,511] -> no init zeroing needed.
// Parity-2 buffer safe: producer at most 1 step ahead of its consumers.
// num: fully block-local, W in registers, 16 independent blocks.
__global__ void __attribute__((amdgpu_flat_work_group_size(1024, 1024)))
__attribute__((amdgpu_waves_per_eu(4, 4))) lfmmi_kernel(
    const float* __restrict__ input, const int* __restrict__ seqlen,
    const float* __restrict__ num_init, const float* __restrict__ num_trans,
    const float* __restrict__ num_final, const int* __restrict__ num_pdf,
    const float* __restrict__ den_init, const float* __restrict__ den_trans,
    const float* __restrict__ den_final, const int* __restrict__ den_pdf,
    float* __restrict__ out, float* __restrict__ ws)
{
  __shared__ __align__(16) unsigned char smem[24832];
  const int tid = threadIdx.x;
  const int bid = blockIdx.x;

  // workspace carve
  u64*      Qc     = (u64*)ws;                         // [2][NGD][GB][CHU]
  float*    DenRes = (float*)(Qc + 2*NGD*GB*CHU);      // [16]
  float*    NumRes = DenRes + 16;                      // [16]
  unsigned* DF     = (unsigned*)(NumRes + 16);         // [NGD][16]
  unsigned* NF     = DF + NGD*16;                      // [16][16]

  const int wv = tid >> 6, ln = tid & 63;

  if (bid < NBD) {
    // ================= DEN =================
    const int g = bid >> 4, r = bid & 15;
    const int cg = tid & 31, kq = tid >> 5;   // tile: cols {cg, cg+32}, k-slice 32
    const int col0 = r * 64;

    float* qs   = (float*)smem;               // [2][2][1024] 16 KB (parity,b,col)
    float* redA = (float*)(smem + 16384);     // [16][64] b0 partials, 4 KB
    float* redB = redA + 1024;                // [16][64] b1 partials, 4 KB
    float* Ms   = (float*)(smem + 24576);     // [2][2] (parity, b)

    // --- W into registers: wA/wB[kk] = exp(trans[kq*32+kk][col0+cg(+32)]) ---
    float wA[32], wB[32];
    {
      const float* wb = den_trans + (size_t)(kq * 32) * SD_ + col0 + cg;
      #pragma unroll
      for (int kk = 0; kk < 32; ++kk) {
        wA[kk] = __expf(wb[(size_t)kk * SD_]);
        wB[kk] = __expf(wb[(size_t)kk * SD_ + 32]);
      }
    }

    const int b0 = 2 * g, b1 = 2 * g + 1;
    const int slen0 = seqlen[b0], slen1 = seqlen[b1];
    const size_t inb0 = (size_t)b0 * T_ * P_, inb1 = (size_t)b1 * T_ * P_;
    int pdf0 = 0;
    if (wv == 0) pdf0 = den_pdf[col0 + ln];

    // --- init publish (t=0, parity 0, tag 0) — wave 0 only ---
    if (wv == 0) {
      u64* ch0 = Qc + ((size_t)(0 * NGD + g) * GB + r) * CHU;
      const float v0 = __expf(den_init[col0 + ln] + input[inb0 + pdf0]);
      const float v1 = __expf(den_init[col0 + ln] + input[inb1 + pdf0]);
      ast64(ch0 + ln, pk(v0, 0u)); ast64(ch0 + 64 + ln, pk(v1, 0u));
      if (r == 0) {
        float m0 = v0, m1 = v1;
        #pragma unroll
        for (int d = 1; d < 64; d <<= 1) {
          m0 = fmaxf(m0, __shfl_xor(m0, d));
          m1 = fmaxf(m1, __shfl_xor(m1, d));
        }
        if (ln == 0) { ast64(ch0 + 128, pk(m0, 0u)); ast64(ch0 + 129, pk(m1, 0u)); }
      }
    }

    float Lr0 = 0.f, Lr1 = 0.f;
    for (int t = 1; t <= 511; ++t) {
      const int pp = (t - 1) & 1, pc = t & 1;
      const unsigned et = (unsigned)(t - 1);
      float e0 = 0.f, e1 = 0.f;
      if (wv == 0) {   // emission gather prefetch
        e0 = input[inb0 + (size_t)t * P_ + pdf0];
        e1 = input[inb1 + (size_t)t * P_ + pdf0];
      }
      // stage q_{t-1}: wave wv polls producer wv's tagged words (data+tag fused)
      {
        const u64* ch = Qc + ((size_t)(pp * NGD + g) * GB + wv) * CHU;
        qs[pp * 2048 + wv * 64 + ln]        = poll_tag(ch + ln, et);
        qs[pp * 2048 + 1024 + wv * 64 + ln] = poll_tag(ch + 64 + ln, et);
        if (wv == 0 && ln < 2) {
          const u64* mh = Qc + ((size_t)(pp * NGD + g) * GB + 0) * CHU + 128;
          Ms[pp * 2 + ln] = poll_tag(mh + ln, et);
        }
      }
      __syncthreads();
      // compute 2c x 2b tile over k-slice 32; q via half-wave LDS broadcast
      const float* q0 = qs + pp * 2048 + kq * 32;
      const float* q1 = q0 + 1024;
      float a00 = 0.f, a01 = 0.f, a10 = 0.f, a11 = 0.f;
      #pragma unroll
      for (int jj = 0; jj < 8; ++jj) {
        const float4 f0 = *(const float4*)(q0 + 4 * jj);
        const float4 f1 = *(const float4*)(q1 + 4 * jj);
        a00 = fmaf(f0.x, wA[4*jj+0], a00); a00 = fmaf(f0.y, wA[4*jj+1], a00);
        a00 = fmaf(f0.z, wA[4*jj+2], a00); a00 = fmaf(f0.w, wA[4*jj+3], a00);
        a01 = fmaf(f0.x, wB[4*jj+0], a01); a01 = fmaf(f0.y, wB[4*jj+1], a01);
        a01 = fmaf(f0.z, wB[4*jj+2], a01); a01 = fmaf(f0.w, wB[4*jj+3], a01);
        a10 = fmaf(f1.x, wA[4*jj+0], a10); a10 = fmaf(f1.y, wA[4*jj+1], a10);
        a10 = fmaf(f1.z, wA[4*jj+2], a10); a10 = fmaf(f1.w, wA[4*jj+3], a10);
        a11 = fmaf(f1.x, wB[4*jj+0], a11); a11 = fmaf(f1.y, wB[4*jj+1], a11);
        a11 = fmaf(f1.z, wB[4*jj+2], a11); a11 = fmaf(f1.w, wB[4*jj+3], a11);
      }
      a00 += __shfl_xor(a00, 32); a01 += __shfl_xor(a01, 32);
      a10 += __shfl_xor(a10, 32); a11 += __shfl_xor(a11, 32);
      if (ln < 32) {   // 4B-stride scalar writes: conflict-free
        redA[wv * 64 + cg] = a00; redA[wv * 64 + 32 + cg] = a01;
        redB[wv * 64 + cg] = a10; redB[wv * 64 + 32 + cg] = a11;
      }
      __syncthreads();
      // wave 0: fold 16 partials, scale, publish tagged words
      if (wv == 0) {
        float acc0 = 0.f, acc1 = 0.f;
        #pragma unroll
        for (int w = 0; w < 16; ++w) {
          acc0 += redA[w * 64 + ln];
          acc1 += redB[w * 64 + ln];
        }
        const float Mv0 = Ms[pp * 2 + 0], Mv1 = Ms[pp * 2 + 1];
        const float v0 = (t < slen0) ? (acc0 / Mv0) * __expf(e0)
                                     : qs[pp * 2048 + col0 + ln];
        const float v1 = (t < slen1) ? (acc1 / Mv1) * __expf(e1)
                                     : qs[pp * 2048 + 1024 + col0 + ln];
        u64* ch = Qc + ((size_t)(pc * NGD + g) * GB + r) * CHU;
        ast64(ch + ln, pk(v0, (unsigned)t));
        ast64(ch + 64 + ln, pk(v1, (unsigned)t));
        if (r == 0) {
          float m0 = v0, m1 = v1;
          #pragma unroll
          for (int d = 1; d < 64; d <<= 1) {
            m0 = fmaxf(m0, __shfl_xor(m0, d));
            m1 = fmaxf(m1, __shfl_xor(m1, d));
          }
          if (ln == 0) {
            ast64(ch + 128, pk(m0, (unsigned)t));
            ast64(ch + 129, pk(m1, (unsigned)t));
            if (t < slen0) Lr0 += __logf(Mv0);
            if (t < slen1) Lr1 += __logf(Mv1);
          }
        }
      }
    }

    // --- epilogue: r==0 blocks reduce final q (t=511, parity 1) ---
    if (r == 0) {
      {
        const u64* ch = Qc + ((size_t)(1 * NGD + g) * GB + wv) * CHU;
        qs[2048 + wv * 64 + ln]        = poll_tag(ch + ln, 511u);
        qs[2048 + 1024 + wv * 64 + ln] = poll_tag(ch + 64 + ln, 511u);
      }
      __syncthreads();
      float* red = redA;   // redA+redB contiguous: 2048 floats
      const int b2e = tid >> 9, ce = tid & 511;
      red[tid] = qs[2048 + b2e * 1024 + ce] * __expf(den_final[ce])
               + qs[2048 + b2e * 1024 + 512 + ce] * __expf(den_final[512 + ce]);
      __syncthreads();
      for (int off = 256; off; off >>= 1) {
        const int base = (tid >= 512) ? 512 : 0, i = tid - base;
        if (i < off) red[base + i] += red[base + i + off];
        __syncthreads();
      }
      if (tid == 0) {
        asf(DenRes + 2 * g,     Lr0 + __logf(red[0]));
        asf(DenRes + 2 * g + 1, Lr1 + __logf(red[512]));
        rsu(DF + g * 16, 0x600D0000u | (unsigned)g);
        if (g == 0) {
          for (int g2 = 0; g2 < NGD; ++g2) wait_eq(DF + g2 * 16, 0x600D0000u | (unsigned)g2);
          for (int b2 = 0; b2 < B_; ++b2)  wait_eq(NF + b2 * 16, 0x600D0100u | (unsigned)b2);
          float sden = 0.f, snum = 0.f;
          for (int i = 0; i < 16; ++i) { sden += alf(DenRes + i); snum += alf(NumRes + i); }
          out[0] = -(snum - sden);
        }
      }
    }
  } else {
    // ================= NUM (fully block-local) =================
    const int b = bid - NBD;
    float* qn   = (float*)smem;               // [2][256] 2 KB
    float* redn = (float*)(smem + 2048);      // [16][256] 16 KB
    float* Ms2  = (float*)(smem + 18432);     // [2]
    const size_t inb = (size_t)b * T_ * P_;
    const int slen = seqlen[b];

    // W regs: wn[kk*4+cc] = exp(trans[16*wv+kk][ln+64*cc])
    float wn[64];
    {
      const float* wb = num_trans + (size_t)(wv * 16) * SN_ + ln;
      #pragma unroll
      for (int kk = 0; kk < 16; ++kk) {
        #pragma unroll
        for (int cc = 0; cc < 4; ++cc)
          wn[kk * 4 + cc] = __expf(wb[(size_t)kk * SN_ + 64 * cc]);
      }
    }
    int pdfn[4] = {0, 0, 0, 0};
    float Lr = 0.f;
    if (wv == 0) {
      #pragma unroll
      for (int cc = 0; cc < 4; ++cc) pdfn[cc] = num_pdf[ln + 64 * cc];
      float mx = 0.f;
      #pragma unroll
      for (int cc = 0; cc < 4; ++cc) {
        const float v = __expf(num_init[ln + 64 * cc] + input[inb + pdfn[cc]]);
        qn[ln + 64 * cc] = v;
        mx = fmaxf(mx, v);
      }
      #pragma unroll
      for (int d = 1; d < 64; d <<= 1) mx = fmaxf(mx, __shfl_xor(mx, d));
      if (ln == 0) Ms2[0] = mx;
    }
    __syncthreads();

    int tlast = 0;
    for (int t = 1; t <= 511; ++t) {
      if (t >= slen) break;      // uniform per block
      tlast = t;
      const int pr = (t - 1) & 1, pw = t & 1;
      float e[4] = {0.f, 0.f, 0.f, 0.f};
      if (wv == 0) {
        #pragma unroll
        for (int cc = 0; cc < 4; ++cc) e[cc] = input[inb + (size_t)t * P_ + pdfn[cc]];
      }
      const float* qp = qn + pr * 256 + wv * 16;
      float ac[4] = {0.f, 0.f, 0.f, 0.f};
      #pragma unroll
      for (int jj = 0; jj < 4; ++jj) {
        const float4 f = *(const float4*)(qp + 4 * jj);
        #pragma unroll
        for (int cc = 0; cc < 4; ++cc) {
          ac[cc] = fmaf(f.x, wn[(4*jj+0)*4+cc], ac[cc]);
          ac[cc] = fmaf(f.y, wn[(4*jj+1)*4+cc], ac[cc]);
          ac[cc] = fmaf(f.z, wn[(4*jj+2)*4+cc], ac[cc]);
          ac[cc] = fmaf(f.w, wn[(4*jj+3)*4+cc], ac[cc]);
        }
      }
      #pragma unroll
      for (int cc = 0; cc < 4; ++cc) redn[wv * 256 + cc * 64 + ln] = ac[cc];
      __syncthreads();
      if (wv == 0) {
        float acc[4] = {0.f, 0.f, 0.f, 0.f};
        #pragma unroll
        for (int w = 0; w < 16; ++w) {
          #pragma unroll
          for (int cc = 0; cc < 4; ++cc) acc[cc] += redn[w * 256 + cc * 64 + ln];
        }
        const float Mv = Ms2[pr];
        const float rM = 1.0f / Mv;
        float mx = 0.f;
        #pragma unroll
        for (int cc = 0; cc < 4; ++cc) {
          const float v = acc[cc] * rM * __expf(e[cc]);
          qn[pw * 256 + ln + 64 * cc] = v;
          mx = fmaxf(mx, v);
        }
        #pragma unroll
        for (int d = 1; d < 64; d <<= 1) mx = fmaxf(mx, __shfl_xor(mx, d));
        if (ln == 0) { Ms2[pw] = mx; Lr += __logf(Mv); }
      }
      __syncthreads();
    }
    const int cur = tlast & 1;
    if (wv == 0) {
      float s = 0.f;
      #pragma unroll
      for (int cc = 0; cc < 4; ++cc)
        s += qn[cur * 256 + ln + 64 * cc] * __expf(num_final[ln + 64 * cc]);
      #pragma unroll
      for (int d = 1; d < 64; d <<= 1) s += __shfl_xor(s, d);
      if (ln == 0) {
        asf(NumRes + b, Lr + __logf(s));
        rsu(NF + b * 16, 0x600D0100u | (unsigned)b);
      }
    }
  }
}

extern "C" void kernel_launch(void* const* d_in, const int* in_sizes, int n_in,
                              void* d_out, int out_size, void* d_ws, size_t ws_size,
                              hipStream_t stream) {
  const float* input     = (const float*)d_in[0];
  const int*   seqlen    = (const int*)  d_in[1];
  const float* num_init  = (const float*)d_in[2];
  const float* num_trans = (const float*)d_in[3];
  const float* num_final = (const float*)d_in[4];
  const int*   num_pdf   = (const int*)  d_in[5];
  const float* den_init  = (const float*)d_in[6];
  const float* den_trans = (const float*)d_in[7];
  const float* den_final = (const float*)d_in[8];
  const int*   den_pdf   = (const int*)  d_in[9];
  float* out = (float*)d_out;
  float* ws  = (float*)d_ws;   // ~280 KB used (tagged chunks + results + flags)

  void* args[] = { &input, &seqlen, &num_init, &num_trans, &num_final, &num_pdf,
                   &den_init, &den_trans, &den_final, &den_pdf, &out, &ws };
  hipLaunchCooperativeKernel((void*)lfmmi_kernel, dim3(NBLK), dim3(NTHR),
                             args, 0, stream);
}

// Round 9
// 1398.423 us; speedup vs baseline: 3.7498x; 1.0675x over previous
//
#include <hip/hip_runtime.h>

#define AG __HIP_MEMORY_SCOPE_AGENT
#define B_ 16
#define T_ 512
#define P_ 2048
#define SN_ 256
#define SD_ 1024
#define NGD 8                 // den groups (one b-pair each)
#define GB 16                 // blocks per den group (64 cols each)
#define NBD (NGD * GB)        // 128 den blocks
#define NBLK (NBD + B_)       // + 16 num blocks = 144
#define NTHR 1024
#define CHU 136               // chunk stride in u64 (64 b0 + 64 b1 + 2 M + pad)

typedef unsigned long long u64;

__device__ __forceinline__ float alf(const float* p){ return __hip_atomic_load(p, __ATOMIC_RELAXED, AG); }
__device__ __forceinline__ void  asf(float* p, float v){ __hip_atomic_store(p, v, __ATOMIC_RELAXED, AG); }
__device__ __forceinline__ void  rsu(unsigned* p, unsigned v){ __hip_atomic_store(p, v, __ATOMIC_RELEASE, AG); }
__device__ __forceinline__ u64   ald64(const u64* p){ return __hip_atomic_load(p, __ATOMIC_RELAXED, AG); }
__device__ __forceinline__ void  ast64(u64* p, u64 v){ __hip_atomic_store(p, v, __ATOMIC_RELAXED, AG); }
__device__ __forceinline__ u64   pk(float v, unsigned t){ return ((u64)t << 32) | (u64)__float_as_uint(v); }
__device__ __forceinline__ void wait_eq(unsigned* p, unsigned v){
  while (__hip_atomic_load(p, __ATOMIC_RELAXED, AG) != v) __builtin_amdgcn_s_sleep(1);
  asm volatile("" ::: "memory");
}
// poll a tagged word until its epoch matches; payload rides in the same 8B.
__device__ __forceinline__ float poll_tag(const u64* p, unsigned et){
  u64 x = ald64(p);
  while ((unsigned)(x >> 32) != et) x = ald64(p);
  return __uint_as_float((unsigned)x);
}

// Exp-space forward recursion, producer/consumer dataflow, ONE barrier/step:
//   q_t[b,c] = (sum_k q_{t-1}[b,k] * W[k,c]) / M[b] * exp(e_t[b,c])
// den: 8 groups x 16 blocks; group owns b-pair {2g,2g+1}; block owns 64 cols.
// Step: wave wv polls its producer's tagged chunk into PRIVATE LDS scratch
// (same-wave write->read: lgkmcnt only, no barrier), computes partials for
// all 128 outputs over its k-slice-64 (W in 64 regs), writes red[parity].
// ONE __syncthreads. Then 8-lane teams fold one output each (2 LDS reads +
// 3 shuffles); team lead publishes its tagged word directly (distributed
// publish — round 8's wave-0-only fold serialized 15 waves behind it).
// Frozen carry kept in lead's REGISTER (v_prev). 2-parity red/Ms: a wave at
// sync(t+1) implies all waves finished fold(t), so parity-(t&1) is only
// rewritten at t+2 — race-free with a single barrier.
// M = 8-col max (r0 wave0/wave8 teams) — any fixed-subset scale is valid
// (self-correcting, within-step spread bounded, fp32 range huge).
// num: fully block-local, W in registers, 16 independent blocks.
__global__ void __attribute__((amdgpu_flat_work_group_size(1024, 1024)))
__attribute__((amdgpu_waves_per_eu(4, 4))) lfmmi_kernel(
    const float* __restrict__ input, const int* __restrict__ seqlen,
    const float* __restrict__ num_init, const float* __restrict__ num_trans,
    const float* __restrict__ num_final, const int* __restrict__ num_pdf,
    const float* __restrict__ den_init, const float* __restrict__ den_trans,
    const float* __restrict__ den_final, const int* __restrict__ den_pdf,
    float* __restrict__ out, float* __restrict__ ws)
{
  __shared__ __align__(16) unsigned char smem[25248];
  const int tid = threadIdx.x;
  const int bid = blockIdx.x;

  // workspace carve
  u64*      Qc     = (u64*)ws;                         // [2][NGD][GB][CHU]
  float*    DenRes = (float*)(Qc + 2*NGD*GB*CHU);      // [16]
  float*    NumRes = DenRes + 16;                      // [16]
  unsigned* DF     = (unsigned*)(NumRes + 16);         // [NGD][16]
  unsigned* NF     = DF + NGD*16;                      // [16][16]

  const int wv = tid >> 6, ln = tid & 63;

  if (bid < NBD) {
    // ================= DEN =================
    const int g = bid >> 4, r = bid & 15;
    const int col0 = r * 64;
    const int tm = ln >> 3, j8 = ln & 7;     // team, lane-in-team
    const int o  = 8 * wv + tm;              // output index this team folds
    const int ob = o >> 6, oc = o & 63;      // batch-half, column of output
    const bool lead = (j8 == 0);

    float* qsW = (float*)smem;               // [16][136] per-wave scratch
    float* red = (float*)(smem + 8704);      // [2][16][129] partials
    float* Ms  = (float*)(smem + 25216);     // [2][2] (parity, b)

    // --- W regs: wreg[j] = exp(trans[64*wv + j][col0 + ln]) ---
    float wreg[64];
    {
      const float* wb = den_trans + (size_t)(64 * wv) * SD_ + col0 + ln;
      #pragma unroll
      for (int j = 0; j < 64; ++j) wreg[j] = __expf(wb[(size_t)j * SD_]);
    }

    const int b0 = 2 * g, b1 = 2 * g + 1;
    const size_t inb0 = (size_t)b0 * T_ * P_, inb1 = (size_t)b1 * T_ * P_;
    int pdfc = 0, slenL = 0; size_t inbL = 0;
    if (lead) {
      pdfc  = den_pdf[col0 + oc];
      inbL  = ob ? inb1 : inb0;
      slenL = seqlen[ob ? b1 : b0];
    }
    u64* myCh0 = Qc + ((size_t)(0 * NGD + g) * GB + r) * CHU;
    u64* myCh1 = Qc + ((size_t)(1 * NGD + g) * GB + r) * CHU;

    // --- init: every team lead computes + publishes its own q0 (tag 0) ---
    float v_prev = 0.f, Lr = 0.f;
    if (lead) {
      v_prev = __expf(den_init[col0 + oc] + input[inbL + pdfc]);
      ast64(myCh0 + o, pk(v_prev, 0u));
    }
    if (r == 0 && (wv == 0 || wv == 8)) {     // M0 from wave0 (b0), M1 from wave8 (b1)
      float mx = lead ? v_prev : 0.f;
      #pragma unroll
      for (int d = 1; d < 64; d <<= 1) mx = fmaxf(mx, __shfl_xor(mx, d));
      if (ln == 0) ast64(myCh0 + 128 + ob, pk(mx, 0u));
    }

    for (int t = 1; t <= 511; ++t) {
      const int pp = (t - 1) & 1, pc = t & 1;
      const unsigned et = (unsigned)(t - 1);
      // lead: prefetch emission gather (hidden behind the poll)
      float e = 0.f;
      if (lead) e = input[inbL + (size_t)t * P_ + pdfc];

      // stage: wave wv polls its producer's chunk into private scratch
      {
        const u64* chs = Qc + ((size_t)(pp * NGD + g) * GB + wv) * CHU;
        const float q0v = poll_tag(chs + ln, et);
        const float q1v = poll_tag(chs + 64 + ln, et);
        qsW[wv * 136 + ln]      = q0v;
        qsW[wv * 136 + 64 + ln] = q1v;
        if (wv == 0 && ln < 2) {
          const u64* mh = Qc + ((size_t)(pp * NGD + g) * GB + 0) * CHU + 128;
          Ms[pp * 2 + ln] = poll_tag(mh + ln, et);
        }
      }
      // compute partials for all 128 outputs over own k-slice (broadcast reads)
      float a0 = 0.f, a1 = 0.f;
      {
        const float* qp = qsW + wv * 136;
        #pragma unroll
        for (int jj = 0; jj < 16; ++jj) {
          const float4 f0 = *(const float4*)(qp + 4 * jj);
          const float4 f1 = *(const float4*)(qp + 64 + 4 * jj);
          a0 = fmaf(f0.x, wreg[4*jj+0], a0); a0 = fmaf(f0.y, wreg[4*jj+1], a0);
          a0 = fmaf(f0.z, wreg[4*jj+2], a0); a0 = fmaf(f0.w, wreg[4*jj+3], a0);
          a1 = fmaf(f1.x, wreg[4*jj+0], a1); a1 = fmaf(f1.y, wreg[4*jj+1], a1);
          a1 = fmaf(f1.z, wreg[4*jj+2], a1); a1 = fmaf(f1.w, wreg[4*jj+3], a1);
        }
      }
      red[(pc * 16 + wv) * 129 + ln]      = a0;   // output o=ln   (b0)
      red[(pc * 16 + wv) * 129 + 64 + ln] = a1;   // output o=64+ln (b1)
      __syncthreads();   // the ONLY barrier per step

      // fold: team folds output o; lead scales + publishes
      float acc = red[(pc * 16 + 2 * j8) * 129 + o]
                + red[(pc * 16 + 2 * j8 + 1) * 129 + o];
      acc += __shfl_xor(acc, 1);
      acc += __shfl_xor(acc, 2);
      acc += __shfl_xor(acc, 4);
      u64* myCh = pc ? myCh1 : myCh0;
      if (lead) {
        const float Mv = Ms[pp * 2 + ob];
        if (t < slenL) v_prev = (acc / Mv) * __expf(e);   // else frozen carry
        ast64(myCh + o, pk(v_prev, (unsigned)t));
      }
      if (r == 0 && (wv == 0 || wv == 8)) {
        float mx = lead ? v_prev : 0.f;
        #pragma unroll
        for (int d = 1; d < 64; d <<= 1) mx = fmaxf(mx, __shfl_xor(mx, d));
        if (ln == 0) {
          ast64(myCh + 128 + ob, pk(mx, (unsigned)t));
          if (t < slenL) Lr += __logf(Ms[pp * 2 + ob]);   // lane0: lead of o=0/64
        }
      }
    }

    // --- epilogue: r==0 blocks reduce final q (t=511, parity 1) ---
    if (r == 0) {
      __syncthreads();
      float* qf = (float*)smem;               // [2][1024]
      float* rs = (float*)(smem + 8192);      // [1024] x2 halves (ends 16384 < red[1] base)
      {
        const u64* ch = Qc + ((size_t)(1 * NGD + g) * GB + wv) * CHU;
        qf[wv * 64 + ln]        = poll_tag(ch + ln, 511u);
        qf[1024 + wv * 64 + ln] = poll_tag(ch + 64 + ln, 511u);
      }
      __syncthreads();
      const int b2e = tid >> 9, ce = tid & 511;
      rs[tid] = qf[b2e * 1024 + ce] * __expf(den_final[ce])
              + qf[b2e * 1024 + 512 + ce] * __expf(den_final[512 + ce]);
      __syncthreads();
      for (int off = 256; off; off >>= 1) {
        const int base = (tid >= 512) ? 512 : 0, i = tid - base;
        if (i < off) rs[base + i] += rs[base + i + off];
        __syncthreads();
      }
      if (tid == 0)   asf(DenRes + 2 * g,     Lr + __logf(rs[0]));     // wave0 lane0: Lr(b0)
      if (tid == 512) asf(DenRes + 2 * g + 1, Lr + __logf(rs[512]));   // wave8 lane0: Lr(b1)
      __syncthreads();
      if (tid == 0) {
        rsu(DF + g * 16, 0x600D0000u | (unsigned)g);
        if (g == 0) {
          for (int g2 = 0; g2 < NGD; ++g2) wait_eq(DF + g2 * 16, 0x600D0000u | (unsigned)g2);
          for (int b2 = 0; b2 < B_; ++b2)  wait_eq(NF + b2 * 16, 0x600D0100u | (unsigned)b2);
          float sden = 0.f, snum = 0.f;
          for (int i = 0; i < 16; ++i) { sden += alf(DenRes + i); snum += alf(NumRes + i); }
          out[0] = -(snum - sden);
        }
      }
    }
  } else {
    // ================= NUM (fully block-local, unchanged from round 8) =================
    const int b = bid - NBD;
    float* qn   = (float*)smem;               // [2][256] 2 KB
    float* redn = (float*)(smem + 2048);      // [16][256] 16 KB
    float* Ms2  = (float*)(smem + 18432);     // [2]
    const size_t inb = (size_t)b * T_ * P_;
    const int slen = seqlen[b];

    float wn[64];
    {
      const float* wb = num_trans + (size_t)(wv * 16) * SN_ + ln;
      #pragma unroll
      for (int kk = 0; kk < 16; ++kk) {
        #pragma unroll
        for (int cc = 0; cc < 4; ++cc)
          wn[kk * 4 + cc] = __expf(wb[(size_t)kk * SN_ + 64 * cc]);
      }
    }
    int pdfn[4] = {0, 0, 0, 0};
    float Lr = 0.f;
    if (wv == 0) {
      #pragma unroll
      for (int cc = 0; cc < 4; ++cc) pdfn[cc] = num_pdf[ln + 64 * cc];
      float mx = 0.f;
      #pragma unroll
      for (int cc = 0; cc < 4; ++cc) {
        const float v = __expf(num_init[ln + 64 * cc] + input[inb + pdfn[cc]]);
        qn[ln + 64 * cc] = v;
        mx = fmaxf(mx, v);
      }
      #pragma unroll
      for (int d = 1; d < 64; d <<= 1) mx = fmaxf(mx, __shfl_xor(mx, d));
      if (ln == 0) Ms2[0] = mx;
    }
    __syncthreads();

    int tlast = 0;
    for (int t = 1; t <= 511; ++t) {
      if (t >= slen) break;
      tlast = t;
      const int pr = (t - 1) & 1, pw = t & 1;
      float e[4] = {0.f, 0.f, 0.f, 0.f};
      if (wv == 0) {
        #pragma unroll
        for (int cc = 0; cc < 4; ++cc) e[cc] = input[inb + (size_t)t * P_ + pdfn[cc]];
      }
      const float* qp = qn + pr * 256 + wv * 16;
      float ac[4] = {0.f, 0.f, 0.f, 0.f};
      #pragma unroll
      for (int jj = 0; jj < 4; ++jj) {
        const float4 f = *(const float4*)(qp + 4 * jj);
        #pragma unroll
        for (int cc = 0; cc < 4; ++cc) {
          ac[cc] = fmaf(f.x, wn[(4*jj+0)*4+cc], ac[cc]);
          ac[cc] = fmaf(f.y, wn[(4*jj+1)*4+cc], ac[cc]);
          ac[cc] = fmaf(f.z, wn[(4*jj+2)*4+cc], ac[cc]);
          ac[cc] = fmaf(f.w, wn[(4*jj+3)*4+cc], ac[cc]);
        }
      }
      #pragma unroll
      for (int cc = 0; cc < 4; ++cc) redn[wv * 256 + cc * 64 + ln] = ac[cc];
      __syncthreads();
      if (wv == 0) {
        float acc[4] = {0.f, 0.f, 0.f, 0.f};
        #pragma unroll
        for (int w = 0; w < 16; ++w) {
          #pragma unroll
          for (int cc = 0; cc < 4; ++cc) acc[cc] += redn[w * 256 + cc * 64 + ln];
        }
        const float Mv = Ms2[pr];
        const float rM = 1.0f / Mv;
        float mx = 0.f;
        #pragma unroll
        for (int cc = 0; cc < 4; ++cc) {
          const float v = acc[cc] * rM * __expf(e[cc]);
          qn[pw * 256 + ln + 64 * cc] = v;
          mx = fmaxf(mx, v);
        }
        #pragma unroll
        for (int d = 1; d < 64; d <<= 1) mx = fmaxf(mx, __shfl_xor(mx, d));
        if (ln == 0) { Ms2[pw] = mx; Lr += __logf(Mv); }
      }
      __syncthreads();
    }
    const int cur = tlast & 1;
    if (wv == 0) {
      float s = 0.f;
      #pragma unroll
      for (int cc = 0; cc < 4; ++cc)
        s += qn[cur * 256 + ln + 64 * cc] * __expf(num_final[ln + 64 * cc]);
      #pragma unroll
      for (int d = 1; d < 64; d <<= 1) s += __shfl_xor(s, d);
      if (ln == 0) {
        asf(NumRes + b, Lr + __logf(s));
        rsu(NF + b * 16, 0x600D0100u | (unsigned)b);
      }
    }
  }
}

extern "C" void kernel_launch(void* const* d_in, const int* in_sizes, int n_in,
                              void* d_out, int out_size, void* d_ws, size_t ws_size,
                              hipStream_t stream) {
  const float* input     = (const float*)d_in[0];
  const int*   seqlen    = (const int*)  d_in[1];
  const float* num_init  = (const float*)d_in[2];
  const float* num_trans = (const float*)d_in[3];
  const float* num_final = (const float*)d_in[4];
  const int*   num_pdf   = (const int*)  d_in[5];
  const float* den_init  = (const float*)d_in[6];
  const float* den_trans = (const float*)d_in[7];
  const float* den_final = (const float*)d_in[8];
  const int*   den_pdf   = (const int*)  d_in[9];
  float* out = (float*)d_out;
  float* ws  = (float*)d_ws;   // ~280 KB used (tagged chunks + results + flags)

  void* args[] = { &input, &seqlen, &num_init, &num_trans, &num_final, &num_pdf,
                   &den_init, &den_trans, &den_final, &den_pdf, &out, &ws };
  hipLaunchCooperativeKernel((void*)lfmmi_kernel, dim3(NBLK), dim3(NTHR),
                             args, 0, stream);
}